// Round 15
// baseline (532.839 us; speedup 1.0000x reference)
//
#include <hip/hip_runtime.h>
#include <math.h>
#include <float.h>

#define H 1080
#define W 1920
#define HWSZ (H*W)
#define NPART 25
#define NCH 26          // heatmap channels in memory (NPART+1)
#define NLIMB 26
#define KTOP 32
#define MID 10
#define RAD 12

#define EPS1 4e-6f           // f32 screen margin (hard two-sided bound ~3.4e-6)
#define EPS2 1.5e-7          // stage-2 margin (hard two-sided bound ~6e-8)
#define B3CAP 65536          // stage-3 list capacity
#define NS 16                // top-k stage-1 slices per channel

// vert_k geometry
#define VB 10                // LDS bounce batch rows (VCHUNK % VB == 0)
#define VXT 16               // x-tile width
#define VCHUNK 100           // output rows per block
// horiz_nms_k geometry (v15 = v14 + restored gx<W screen guard)
#define TH2S 30              // screened rows per block (1080 = 36*30)
#define TW2B 256             // block screen width (pow2)
#define VTC2 282             // vt logical cols (x0-13 .. x0+268)
#define VTS2 283             // vt stride f32 (odd -> bank floor)
#define CANDC 1024           // LDS candidate cap (expected ~150/block; overflow->global)

// Output layout (floats): px[25*32] py[25*32] score[25*32] mask[25*32] conn[26*32*32]
#define OFF_PY   800
#define OFF_SC   1600
#define OFF_MK   2400
#define OFF_CONN 3200

__device__ __constant__ int LIMBS_d[NLIMB * 2] = {
    1,8, 1,2, 1,5, 2,3, 3,4, 5,6, 6,7, 8,9, 9,10, 10,11, 8,12, 12,13, 13,14,
    1,0, 0,15, 15,16, 0,17, 0,18, 14,19, 19,20, 14,21, 11,22, 22,23, 11,24, 2,17, 5,18
};

__device__ __forceinline__ int symH(int y) {
    if (y < 0) return -1 - y;
    if (y >= H) return 2 * H - 1 - y;
    return y;
}
__device__ __forceinline__ int symW(int x) {
    if (x < 0) return -1 - x;
    if (x >= W) return 2 * W - 1 - x;
    return x;
}

// ---------------------------------------------------------------------------
// Weight init: once per launch. Same FP op order as all prior rounds.
// ---------------------------------------------------------------------------
__global__ void winit_k(double* __restrict__ gw64, float* __restrict__ gw32)
{
    if (threadIdx.x == 0) {
        double wd[25]; double s = 0.0;
        for (int t = 0; t < 25; ++t) {
            double u = (double)(t - 12) / 3.0;
            wd[t] = exp(-0.5 * u * u); s += wd[t];
        }
        for (int t = 0; t < 13; ++t) {
            double w = wd[t] / s;
            gw64[t] = w;
            gw32[t] = (float)w;
        }
    }
}

// ---------------------------------------------------------------------------
// Pass 1: vertical blur (f64 rolling window) -> v32 planar. c==25 threads
// skip global loads (their results are never stored).
// ---------------------------------------------------------------------------
__global__ __launch_bounds__(416) void vert_k(
    const float* __restrict__ hm, float* __restrict__ vpl,
    const double* __restrict__ gw64)
{
    __shared__ float ldv[VB][26][17];   // 17.7 KB
    const int tid = threadIdx.x;
    const int x0 = blockIdx.x * VXT;
    const int ys = blockIdx.y * VCHUNK;
    const int c  = tid % 26;
    const int xo = tid / 26;           // 0..15
    const int gx = x0 + xo;
    const bool act = (c < 25);

    double ws[13];
    #pragma unroll
    for (int t = 0; t < 13; ++t) ws[t] = gw64[t];   // uniform -> scalar loads

    const size_t cstr = (size_t)W * NCH;
    const size_t base = (size_t)gx * NCH + c;
    const bool yint = (ys >= 12) && (ys + VCHUNK + 11 < H);

    double win[25];
    #pragma unroll
    for (int k = 0; k < 25; ++k) win[k] = 0.0;
    if (act) {
        if (yint) {
            const float* p0 = hm + (size_t)(ys - 12) * cstr + base;
            #pragma unroll
            for (int k = 0; k < 24; ++k) { win[k] = (double)*p0; p0 += cstr; }
        } else {
            #pragma unroll
            for (int k = 0; k < 24; ++k) {
                int ry = symH(ys - 12 + k);
                win[k] = (double)hm[(size_t)ry * cstr + base];
            }
        }
    }

    const float* pn = hm + (size_t)symH(ys + 12) * cstr + base;  // +12 row (fast path)

    #pragma unroll 1
    for (int blk = 0; blk < VCHUNK; blk += 25) {
        #pragma unroll
        for (int p = 0; p < 25; ++p) {
            const int yo = blk + p;
            const int y  = ys + yo;
            double nv = 0.0;
            if (yint) { if (act) nv = (double)*pn; pn += cstr; }
            else if (act) { int ry = symH(y + 12); nv = (double)hm[(size_t)ry * cstr + base]; }
            win[(p + 24) % 25] = nv;
            double acc = 0.0;
            #pragma unroll
            for (int t = 0; t < 25; ++t)
                acc = fma(ws[t < 13 ? t : 24 - t], win[(p + t) % 25], acc);
            if (act) ldv[yo % VB][c][xo] = (float)acc;
            if ((yo % VB) == VB - 1) {
                __syncthreads();
                const int c2 = tid >> 4, x2 = tid & 15;
                if (c2 < 25) {
                    const int yb = ys + yo - (VB - 1);
                    #pragma unroll
                    for (int i = 0; i < VB; ++i) {
                        int yr = yb + i;
                        if (yr < H)
                            vpl[(size_t)c2 * HWSZ + (size_t)yr * W + x0 + x2] = ldv[i][c2][x2];
                    }
                }
                __syncthreads();
            }
        }
    }
}

// f64 horizontal eval over the LDS vt tile (v32 values), same source bits as
// the old vpl-based smh2; f64 summation noise ~1e-15 << EPS2 margin.
__device__ __forceinline__ double smh2_lds(const float (*vt)[VTS2],
                                           const double* __restrict__ gw64,
                                           int row, int cb)
{
    double acc = 0.0;
    #pragma unroll
    for (int t = 0; t < 25; ++t) {
        int wi = t < 13 ? t : 24 - t;
        acc = fma(gw64[wi], (double)vt[row][cb + t], acc);
    }
    return acc;
}

// ---------------------------------------------------------------------------
// Pass 2 (v15): f32 horizontal blur + NMS screen. NO smt: up/dn via lane
// shuffles (thread (r+-1,g) = lane +-1 within the same 32-lane half-wave for
// all screened rows r in [1,30]). vt stays live -> stage-2 EPS2 recheck runs
// INLINE from LDS; ambiguous entries escalate to bl3.
// v15 fix: restored the gx < W screen guard (grid is 2048 wide vs W=1920;
// dropping it in v14 emitted symW-reflected mirror peaks -> absmax 1868).
// ---------------------------------------------------------------------------
__global__ __launch_bounds__(512) void horiz_nms_k(
    const float* __restrict__ vpl, const float* __restrict__ hm,
    float* __restrict__ cval, int* __restrict__ cidx,
    int* __restrict__ counters, unsigned int* __restrict__ bl3,
    const float* __restrict__ gw32, const double* __restrict__ gw64, int cap)
{
    __shared__ __align__(16) float vt[32][VTS2];   // 36.2 KB, live to the end
    __shared__ unsigned short cand[CANDC];         // 2 KB
    __shared__ int lcount, gbase;

    const int tid = threadIdx.x;
    const int r   = tid & 31;          // vt/compute row 0..31
    const int g   = tid >> 5;          // col group 0..15
    const int ch  = blockIdx.z;
    const int x0  = blockIdx.x * TW2B;
    const int y0  = blockIdx.y * TH2S;
    const float* vp = vpl + (size_t)ch * HWSZ;

    if (tid == 0) lcount = 0;
    float w32[13];
    #pragma unroll
    for (int t = 0; t < 13; ++t) w32[t] = gw32[t];   // uniform -> scalar loads

    // ---- load vt: thread (lr = tid>>4, lc0 = tid&15) loads cols lc0+16j
    {
        const int lr  = tid >> 4;      // 0..31
        const int lc0 = tid & 15;
        int gy = y0 - 1 + lr;
        gy = gy < 0 ? 0 : (gy >= H ? H - 1 : gy);
        const float* rowp = vp + (size_t)gy * W;
        const bool xint = (x0 >= 13) && (x0 + (VTC2 - 13) <= W);
        if (xint) {
            const float* p = rowp + (x0 - 13) + lc0;
            #pragma unroll
            for (int j = 0; j < 18; ++j) {
                int cc = lc0 + 16 * j;
                if (cc < VTC2) vt[lr][cc] = p[16 * j];
            }
        } else {
            #pragma unroll
            for (int j = 0; j < 18; ++j) {
                int cc = lc0 + 16 * j;
                if (cc < VTC2) vt[lr][cc] = rowp[symW(x0 - 13 + cc)];
            }
        }
    }
    __syncthreads();   // also publishes lcount init

    // ---- horizontal: a[k] = s(y0-1+r, x0 - 1 + g*16 + k), k = 0..17
    float a[18];
    #pragma unroll
    for (int k = 0; k < 18; ++k) a[k] = 0.f;
    {
        const float* vrow = &vt[r][g * 16];
        #pragma unroll
        for (int t = 0; t < 42; ++t) {
            float x = vrow[t];
            #pragma unroll
            for (int k = 0; k < 18; ++k)
                if (t >= k && t < k + 25) {
                    int wi = t - k; wi = wi < 13 ? wi : 24 - wi;
                    a[k] = fmaf(w32[wi], x, a[k]);   // tap-ascending, same as R9-R13
                }
        }
    }

    // ---- up/dn rows via lane shuffles (sources valid for screened r in [1,30])
    float upv[16], dnv[16];
    #pragma unroll
    for (int k = 0; k < 16; ++k) {
        upv[k] = __shfl_up(a[k + 1], 1, 64);
        dnv[k] = __shfl_down(a[k + 1], 1, 64);
    }

    // ---- screen + inline stage-2; vt still live (no overlay)
    const int gy = y0 - 1 + r;   // this thread's pixel row (ly = r-1)
    if (r >= 1 && r <= TH2S && gy < H) {
        const int ly = r - 1;
        #pragma unroll
        for (int k = 0; k < 16; ++k) {
            int gx = x0 + g * 16 + k;
            if (gx >= W) continue;                     // v15 FIX (v14 dropped this)
            float s  = a[k + 1];
            float lv = (gx == 0) ? 0.f : a[k];
            float rv = (gx + 1 >= W) ? 0.f : a[k + 2];
            float u0 = (gy - 1 >= 0) ? upv[k] : 0.f;   // z_row semantics
            float d0v = (gy + 1 < H) ? dnv[k] : 0.f;
            float dT = s - 0.1f;
            float d0 = s - u0;
            float d1 = s - d0v;
            float d2 = s - lv;
            float d3 = s - rv;
            int flags = (fabsf(dT) <= EPS1 ? 1 : 0)
                      | (fabsf(d0) <= EPS1 ? 2 : 0)
                      | (fabsf(d1) <= EPS1 ? 4 : 0)
                      | (fabsf(d2) <= EPS1 ? 8 : 0)
                      | (fabsf(d3) <= EPS1 ? 16 : 0);
            bool emit = false;
            bool esc  = false;
            if (!flags) {
                emit = (dT > 0.f && d0 >= 0.f && d1 >= 0.f && d2 >= 0.f && d3 >= 0.f);
            } else {
                bool fail = (!(flags & 1)  && dT <= 0.f) ||
                            (!(flags & 2)  && d0 <  0.f) ||
                            (!(flags & 4)  && d1 <  0.f) ||
                            (!(flags & 8)  && d2 <  0.f) ||
                            (!(flags & 16) && d3 <  0.f);
                if (!fail) {
                    // inline stage-2: f64 horizontal from LDS v32 (rare path)
                    const int cb = g * 16 + k + 1;   // pixel eval col base
                    double s2 = smh2_lds(vt, gw64, r, cb);
                    bool dead = false;
                    if (flags & 1) {
                        double d = s2 - 0.1;
                        if (d <= -EPS2) dead = true; else if (d < EPS2) esc = true;
                    }
                    if (!dead && (flags & 2)) {
                        double nv = (gy - 1 >= 0) ? smh2_lds(vt, gw64, r - 1, cb) : 0.0;
                        double d = s2 - nv;
                        if (d <= -EPS2) dead = true; else if (d < EPS2) esc = true;
                    }
                    if (!dead && (flags & 4)) {
                        double nv = (gy + 1 < H) ? smh2_lds(vt, gw64, r + 1, cb) : 0.0;
                        double d = s2 - nv;
                        if (d <= -EPS2) dead = true; else if (d < EPS2) esc = true;
                    }
                    if (!dead && (flags & 8)) {
                        double nv = (gx - 1 >= 0) ? smh2_lds(vt, gw64, r, cb - 1) : 0.0;
                        double d = s2 - nv;
                        if (d <= -EPS2) dead = true; else if (d < EPS2) esc = true;
                    }
                    if (!dead && (flags & 16)) {
                        double nv = (gx + 1 < W) ? smh2_lds(vt, gw64, r, cb + 1) : 0.0;
                        double d = s2 - nv;
                        if (d <= -EPS2) dead = true; else if (d < EPS2) esc = true;
                    }
                    if (!dead) {
                        if (esc) {
                            unsigned int ent = ((unsigned int)ch << 26)
                                             | ((unsigned int)flags << 21)
                                             | (unsigned int)(gy * W + gx);
                            int gp = atomicAdd(&counters[33], 1);
                            if (gp < B3CAP) bl3[gp] = ent;
                        } else emit = true;
                    }
                }
            }
            if (emit) {
                int pos = atomicAdd(&lcount, 1);
                if (pos < CANDC) cand[pos] = (unsigned short)((ly << 8) | (g * 16 + k));
                else {  // overflow (improbable): direct global append
                    int gpix = gy * W + gx;
                    int p = atomicAdd(&counters[ch], 1);
                    if (p < cap) {
                        cval[(size_t)ch * cap + p] = hm[(size_t)gpix * NCH + ch];
                        cidx[(size_t)ch * cap + p] = gpix;
                    }
                }
            }
        }
    }
    __syncthreads();

    if (tid == 0) {
        int nl = lcount < CANDC ? lcount : CANDC;
        gbase = atomicAdd(&counters[ch], nl);
    }
    __syncthreads();
    int n = lcount < CANDC ? lcount : CANDC;
    int b = gbase;
    for (int i = tid; i < n; i += 512) {
        int p = b + i;
        if (p < cap) {
            int e = cand[i];
            int ly = e >> 8, lx = e & 255;
            int gpix = (y0 + ly) * W + (x0 + lx);
            cval[(size_t)ch * cap + p] = hm[(size_t)gpix * NCH + ch];  // original bits
            cidx[(size_t)ch * cap + p] = gpix;
        }
    }
}

// ---------------------------------------------------------------------------
// Stage-3: fully exact 2D f64 from channels-last hm, tiny escalation list.
// ---------------------------------------------------------------------------
__device__ double sm64_eval(const float* __restrict__ hm, int ch,
                            const double* w64s, int y, int x)
{
    int lane = threadIdx.x & 63;
    double colsum = 0.0;
    if (lane < 25) {
        int cx = symW(x - RAD + lane);
        float xv[25];
        #pragma unroll
        for (int t = 0; t < 25; t++) {
            int ry = symH(y - RAD + t);
            xv[t] = hm[((size_t)ry * W + cx) * NCH + ch];
        }
        #pragma unroll
        for (int t = 0; t < 25; t++)
            colsum = fma(w64s[t < 13 ? t : 24 - t], (double)xv[t], colsum);
    }
    double acc = 0.0;
    for (int ci = 0; ci < 25; ci++) {
        double cs = __shfl(colsum, ci, 64);
        acc = fma(w64s[ci < 13 ? ci : 24 - ci], cs, acc);
    }
    return acc;
}

__global__ __launch_bounds__(64) void recheck3_k(
    const float* __restrict__ hm,
    float* __restrict__ cval, int* __restrict__ cidx,
    int* __restrict__ counters, const unsigned int* __restrict__ bl3,
    const double* __restrict__ gw64, int cap)
{
    __shared__ double w64s[13];
    const int tid = threadIdx.x;
    if (tid < 13) w64s[tid] = gw64[tid];
    __syncthreads();

    int total = counters[33];
    if (total > B3CAP) total = B3CAP;
    for (int e = blockIdx.x; e < total; e += gridDim.x) {
        unsigned int ent = bl3[e];
        int ch    = (int)(ent >> 26);
        int flags = (int)((ent >> 21) & 31);
        int gpix  = (int)(ent & 0x1FFFFFu);
        int gy = gpix / W, gx = gpix - gy * W;
        double sc = sm64_eval(hm, ch, w64s, gy, gx);
        bool ok = (flags & 1) ? (sc > 0.1) : true;
        if (ok && (flags & 2))  { double nv = (gy - 1 >= 0) ? sm64_eval(hm, ch, w64s, gy - 1, gx) : 0.0; ok = (sc >= nv); }
        if (ok && (flags & 4))  { double nv = (gy + 1 <  H) ? sm64_eval(hm, ch, w64s, gy + 1, gx) : 0.0; ok = (sc >= nv); }
        if (ok && (flags & 8))  { double nv = (gx - 1 >= 0) ? sm64_eval(hm, ch, w64s, gy, gx - 1) : 0.0; ok = (sc >= nv); }
        if (ok && (flags & 16)) { double nv = (gx + 1 <  W) ? sm64_eval(hm, ch, w64s, gy, gx + 1) : 0.0; ok = (sc >= nv); }
        if (tid == 0 && ok) {
            int p = atomicAdd(&counters[ch], 1);
            if (p < cap) {
                cval[(size_t)ch * cap + p] = hm[(size_t)gpix * NCH + ch];
                cidx[(size_t)ch * cap + p] = gpix;
            }
        }
    }
}

// ---------------------------------------------------------------------------
// Fallback: exact-f64 gather version (used only if ws too small)
// ---------------------------------------------------------------------------
#define TH 32
#define TW 64
#define LR (TH + 2*RAD + 2)
#define LC 90
#define VRR 34
#define VC (TW + 2*RAD + 2)
#define SR 34
#define SC 66
__global__ __launch_bounds__(256) void blur_peaks_gather(
    const float* __restrict__ hm,
    float* __restrict__ cval, int* __restrict__ cidx,
    int* __restrict__ counters, int cap)
{
    __shared__ float  in_t[LR][LC];
    __shared__ double v[VRR][VC];
    __shared__ double smv[SR][SC];
    __shared__ double wgt[2 * RAD + 1];
    __shared__ double wsum;

    const int tid = threadIdx.x;
    const int ch  = blockIdx.x;
    const int x0  = blockIdx.y * TW;
    const int y0  = blockIdx.z * TH;

    if (tid < 2 * RAD + 1) {
        double t = (double)(tid - RAD) / 3.0;
        wgt[tid] = exp(-0.5 * t * t);
    }
    __syncthreads();
    if (tid == 0) {
        double s = 0.0;
        for (int i = 0; i < 2 * RAD + 1; i++) s += wgt[i];
        wsum = s;
    }
    __syncthreads();
    if (tid < 2 * RAD + 1) wgt[tid] /= wsum;

    for (int i = tid; i < LR * LC; i += 256) {
        int r = i / LC, c = i % LC;
        int gy = symH(y0 - RAD - 1 + r);
        int gx = symW(x0 - RAD - 1 + c);
        in_t[r][c] = hm[((size_t)gy * W + gx) * NCH + ch];
    }
    __syncthreads();

    for (int i = tid; i < VRR * VC; i += 256) {
        int r = i / VC, c = i % VC;
        double acc = 0.0;
        #pragma unroll
        for (int t = 0; t < 2 * RAD + 1; t++)
            acc = fma(wgt[t], (double)in_t[r + t][c], acc);
        v[r][c] = acc;
    }
    __syncthreads();

    for (int i = tid; i < SR * SC; i += 256) {
        int r = i / SC, cc = i % SC;
        int gy = y0 - 1 + r;
        int gx = x0 - 1 + cc;
        double acc = 0.0;
        if (gy >= 0 && gy < H && gx >= 0 && gx < W) {
            #pragma unroll
            for (int t = 0; t < 2 * RAD + 1; t++)
                acc = fma(wgt[t], v[r][cc + t], acc);
        }
        smv[r][cc] = acc;
    }
    __syncthreads();

    for (int i = tid; i < TH * TW; i += 256) {
        int ly = i / TW, lx = i % TW;
        int gy = y0 + ly, gx = x0 + lx;
        if (gy >= H || gx >= W) continue;
        double s = smv[ly + 1][lx + 1];
        if (s > 0.1 &&
            s >= smv[ly][lx + 1] && s >= smv[ly + 2][lx + 1] &&
            s >= smv[ly + 1][lx] && s >= smv[ly + 1][lx + 2]) {
            float val = in_t[ly + RAD + 1][lx + RAD + 1];
            int pos = atomicAdd(&counters[ch], 1);
            if (pos < cap) {
                cval[(size_t)ch * cap + pos] = val;
                cidx[(size_t)ch * cap + pos] = gy * W + gx;
            }
        }
    }
}

// ---------------------------------------------------------------------------
// Kernel B1: per-(channel, slice) exact top-32 -> packed keys to s1.
// ---------------------------------------------------------------------------
#define BT 128
__global__ __launch_bounds__(BT) void topk1_kernel(
    const float* __restrict__ cval, const int* __restrict__ cidx,
    const int* __restrict__ counters, int cap,
    unsigned long long* __restrict__ s1)
{
    __shared__ unsigned long long lk[KTOP * BT];
    __shared__ unsigned long long rk[BT];
    __shared__ int rw[BT];
    __shared__ int winner;

    const int tid = threadIdx.x;
    const int sl  = blockIdx.x;   // slice
    const int ch  = blockIdx.y;
    int n = counters[ch];
    if (n > cap) n = cap;

    int cnt = 0;
    for (int j = sl * BT + tid; j < n; j += NS * BT) {
        float v = cval[(size_t)ch * cap + j];
        unsigned int u = __float_as_uint(v);
        u = (u & 0x80000000u) ? ~u : (u | 0x80000000u);   // monotonic key
        unsigned long long key =
            ((unsigned long long)u << 32) |
            (unsigned int)(0xFFFFFFFFu - (unsigned int)cidx[(size_t)ch * cap + j]);
        if (cnt == KTOP) {
            if (key <= lk[(KTOP - 1) * BT + tid]) continue;
            cnt = KTOP - 1;
        }
        int i = cnt;
        while (i > 0 && key > lk[(i - 1) * BT + tid]) {
            lk[i * BT + tid] = lk[(i - 1) * BT + tid];
            i--;
        }
        lk[i * BT + tid] = key;
        cnt++;
    }
    int cur = 0;
    __syncthreads();

    for (int k = 0; k < KTOP; k++) {
        rk[tid] = (cur < cnt) ? lk[cur * BT + tid] : 0ULL;
        rw[tid] = tid;
        __syncthreads();
        for (int s = BT / 2; s > 0; s >>= 1) {
            if (tid < s) {
                if (rk[tid + s] > rk[tid]) { rk[tid] = rk[tid + s]; rw[tid] = rw[tid + s]; }
            }
            __syncthreads();
        }
        if (tid == 0) {
            winner = rw[0];
            s1[((size_t)ch * NS + sl) * KTOP + k] = rk[0];   // 0 = empty pad
        }
        __syncthreads();
        if (tid == winner && cur < cnt) cur++;
        __syncthreads();
    }
}

// ---------------------------------------------------------------------------
// Kernel B2: per-channel merge of NS*32=512 keys via LDS bitonic sort (desc).
// ---------------------------------------------------------------------------
__global__ __launch_bounds__(BT) void topk2_kernel(
    const unsigned long long* __restrict__ s1,
    const int* __restrict__ counters, int cap, float* __restrict__ out)
{
    __shared__ unsigned long long sk[NS * KTOP];   // 512 keys, 4 KB
    const int tid = threadIdx.x;
    const int ch  = blockIdx.x;

    for (int i = tid; i < NS * KTOP; i += BT)
        sk[i] = s1[(size_t)ch * NS * KTOP + i];
    __syncthreads();

    for (int k = 2; k <= NS * KTOP; k <<= 1) {
        for (int j = k >> 1; j > 0; j >>= 1) {
            for (int t = tid; t < NS * KTOP; t += BT) {
                int ixj = t ^ j;
                if (ixj > t) {
                    unsigned long long a = sk[t], b = sk[ixj];
                    bool sw = ((t & k) == 0) ? (a < b) : (a > b);
                    if (sw) { sk[t] = b; sk[ixj] = a; }
                }
            }
            __syncthreads();
        }
    }

    int n = counters[ch];
    if (n > cap) n = cap;
    if (tid < KTOP) {
        unsigned long long bk = sk[tid];
        float px, py, sc, mk;
        if (bk == 0ULL) {
            int fake = tid - n; if (fake < 0) fake = 0;
            px = (float)(fake % W); py = (float)(fake / W); sc = 0.f; mk = 0.f;
        } else {
            unsigned int u = (unsigned int)(bk >> 32);
            unsigned int fb = (u & 0x80000000u) ? (u ^ 0x80000000u) : ~u;
            float v = __uint_as_float(fb);
            int idx = (int)(0xFFFFFFFFu - (unsigned int)(bk & 0xFFFFFFFFu));
            px = (float)(idx % W); py = (float)(idx / W); sc = v; mk = 1.f;
        }
        out[ch * KTOP + tid]          = px;
        out[OFF_PY + ch * KTOP + tid] = py;
        out[OFF_SC + ch * KTOP + tid] = sc;
        out[OFF_MK + ch * KTOP + tid] = mk;
    }
}

// ---------------------------------------------------------------------------
// Fallback single-stage top-k (ws-too-small path only)
// ---------------------------------------------------------------------------
__global__ __launch_bounds__(BT) void topk_kernel(
    const float* __restrict__ cval, const int* __restrict__ cidx,
    const int* __restrict__ counters, int cap, float* __restrict__ out)
{
    __shared__ unsigned long long lk[KTOP * BT];
    __shared__ unsigned long long rk[BT];
    __shared__ int rw[BT];
    __shared__ int winner;

    const int tid = threadIdx.x;
    const int ch  = blockIdx.x;
    int n = counters[ch];
    if (n > cap) n = cap;

    int cnt = 0;
    for (int j = tid; j < n; j += BT) {
        float v = cval[(size_t)ch * cap + j];
        unsigned int u = __float_as_uint(v);
        u = (u & 0x80000000u) ? ~u : (u | 0x80000000u);
        unsigned long long key =
            ((unsigned long long)u << 32) |
            (unsigned int)(0xFFFFFFFFu - (unsigned int)cidx[(size_t)ch * cap + j]);
        if (cnt == KTOP) {
            if (key <= lk[(KTOP - 1) * BT + tid]) continue;
            cnt = KTOP - 1;
        }
        int i = cnt;
        while (i > 0 && key > lk[(i - 1) * BT + tid]) {
            lk[i * BT + tid] = lk[(i - 1) * BT + tid];
            i--;
        }
        lk[i * BT + tid] = key;
        cnt++;
    }
    int cur = 0;
    __syncthreads();

    for (int k = 0; k < KTOP; k++) {
        rk[tid] = (cur < cnt) ? lk[cur * BT + tid] : 0ULL;
        rw[tid] = tid;
        __syncthreads();
        for (int s = BT / 2; s > 0; s >>= 1) {
            if (tid < s) {
                if (rk[tid + s] > rk[tid]) { rk[tid] = rk[tid + s]; rw[tid] = rw[tid + s]; }
            }
            __syncthreads();
        }
        if (tid == 0) {
            winner = rw[0];
            unsigned long long bk = rk[0];
            float px, py, sc, mk;
            if (bk == 0ULL) {
                int fake = k - n; if (fake < 0) fake = 0;
                px = (float)(fake % W); py = (float)(fake / W); sc = 0.f; mk = 0.f;
            } else {
                unsigned int u = (unsigned int)(bk >> 32);
                unsigned int fb = (u & 0x80000000u) ? (u ^ 0x80000000u) : ~u;
                float v = __uint_as_float(fb);
                int idx = (int)(0xFFFFFFFFu - (unsigned int)(bk & 0xFFFFFFFFu));
                px = (float)(idx % W); py = (float)(idx / W); sc = v; mk = 1.f;
            }
            out[ch * KTOP + k]          = px;
            out[OFF_PY + ch * KTOP + k] = py;
            out[OFF_SC + ch * KTOP + k] = sc;
            out[OFF_MK + ch * KTOP + k] = mk;
        }
        __syncthreads();
        if (tid == winner && cur < cnt) cur++;
        __syncthreads();
    }
}

// ---------------------------------------------------------------------------
// Kernel C: limb connection scores (26 x 32 x 32)
// ---------------------------------------------------------------------------
__global__ __launch_bounds__(1024) void limbs_kernel(
    const float* __restrict__ pk, const float* __restrict__ paf,
    float* __restrict__ out)
{
    const int l = blockIdx.x;
    const int tid = threadIdx.x;
    const int i = tid >> 5;
    const int j = tid & 31;
    const int A = LIMBS_d[2 * l], B = LIMBS_d[2 * l + 1];

    float ax = pk[A * KTOP + i],          ay = pk[OFF_PY + A * KTOP + i];
    float ma = pk[OFF_MK + A * KTOP + i];
    float bx = pk[B * KTOP + j],          by = pk[OFF_PY + B * KTOP + j];
    float mb = pk[OFF_MK + B * KTOP + j];

    float vx = bx - ax, vy = by - ay;
    float norm = sqrtf(vx * vx + vy * vy) + 1e-10f;
    float ux = vx / norm, uy = vy / norm;

    const float step = 1.0f / 9.0f;
    float sum = 0.f;
    #pragma unroll
    for (int m = 0; m < MID; m++) {
        float t = (float)m * step;
        int sx = (int)rintf(ax + vx * t);
        int sy = (int)rintf(ay + vy * t);
        const float* p = paf + ((size_t)sy * W + sx) * (2 * NLIMB) + 2 * l;
        sum += p[0] * ux + p[1] * uy;
    }
    float score = sum / (float)MID;
    score = score < 0.f ? 0.f : (score > 1.f ? 1.f : score);
    float res = (ma != 0.f && mb != 0.f) ? score : 0.f;
    out[OFF_CONN + l * (KTOP * KTOP) + i * KTOP + j] = res;
}

// ---------------------------------------------------------------------------
extern "C" void kernel_launch(void* const* d_in, const int* in_sizes, int n_in,
                              void* d_out, int out_size, void* d_ws, size_t ws_size,
                              hipStream_t stream)
{
    const float* hm  = (const float*)d_in[0];
    const float* paf = (const float*)d_in[1];
    float* out = (float*)d_out;

    const size_t vpl_bytes = (size_t)NPART * HWSZ * sizeof(float);  // ~207.4 MB
    const size_t b3_bytes  = (size_t)B3CAP * 4;                     // 256 KB
    const size_t s1_bytes  = (size_t)NPART * NS * KTOP * 8;         // 100 KB
    const size_t head = 512;   // counters [0,256) + weights [256,512)

    bool pathA = false;
    int cap = 1;
    if (ws_size > head + vpl_bytes + b3_bytes + s1_bytes
                 + (size_t)NPART * 8 * 4096 + 1024) {
        size_t avail = ws_size - head - vpl_bytes - b3_bytes - s1_bytes - 1024;
        long long c = (long long)(avail / ((size_t)NPART * 8));
        cap = c > 65536 ? 65536 : (int)c;
        pathA = true;
    } else {
        size_t avail = ws_size > head ? ws_size - head : 0;
        long long c = (long long)(avail / ((size_t)NPART * 8));
        cap = c > 65536 ? 65536 : (int)c;
        if (cap < 1) cap = 1;
    }

    int*    counters = (int*)d_ws;
    double* gw64 = (double*)((char*)d_ws + 256);    // 13 doubles
    float*  gw32 = (float*)((char*)d_ws + 384);     // 13 floats
    float* cval = (float*)((char*)d_ws + head);
    int*   cidx = (int*)(cval + (size_t)NPART * cap);
    unsigned long long* s1 = (unsigned long long*)(cidx + (size_t)NPART * cap);
    unsigned int* bl3 = (unsigned int*)(s1 + (pathA ? (size_t)NPART * NS * KTOP : 0));
    float* vpl = (float*)(bl3 + (pathA ? (size_t)B3CAP : 0));
    vpl = (float*)(((uintptr_t)vpl + 255) & ~(uintptr_t)255);

    hipMemsetAsync(d_ws, 0, 256, stream);

    if (pathA) {
        winit_k<<<1, 64, 0, stream>>>(gw64, gw32);
        dim3 g1(W / VXT, (H + VCHUNK - 1) / VCHUNK);                // 120 x 11
        vert_k<<<g1, 416, 0, stream>>>(hm, vpl, gw64);
        dim3 g2((W + TW2B - 1) / TW2B, H / TH2S, NPART);            // 8 x 36 x 25
        horiz_nms_k<<<g2, 512, 0, stream>>>(vpl, hm, cval, cidx, counters, bl3, gw32, gw64, cap);
        recheck3_k<<<128, 64, 0, stream>>>(hm, cval, cidx, counters, bl3, gw64, cap);
        dim3 gt(NS, NPART);
        topk1_kernel<<<gt, BT, 0, stream>>>(cval, cidx, counters, cap, s1);
        topk2_kernel<<<NPART, BT, 0, stream>>>(s1, counters, cap, out);
    } else {
        dim3 gA(NPART, (W + TW - 1) / TW, (H + TH - 1) / TH);
        blur_peaks_gather<<<gA, 256, 0, stream>>>(hm, cval, cidx, counters, cap);
        topk_kernel<<<NPART, BT, 0, stream>>>(cval, cidx, counters, cap, out);
    }
    limbs_kernel<<<NLIMB, 1024, 0, stream>>>(out, paf, out);
}

// Round 16
// 441.819 us; speedup vs baseline: 1.2060x; 1.2060x over previous
//
#include <hip/hip_runtime.h>
#include <math.h>
#include <float.h>

#define H 1080
#define W 1920
#define HWSZ (H*W)
#define NPART 25
#define NCH 26          // heatmap channels in memory (NPART+1)
#define NLIMB 26
#define KTOP 32
#define MID 10
#define RAD 12

#define EPS1 4e-6f           // f32 screen margin (hard two-sided bound ~3.4e-6)
#define EPS2 1.5e-7          // stage-2 margin (hard two-sided bound ~6e-8)
#define BLCAP (1 << 20)      // stage-2 list capacity
#define NS 16                // top-k stage-1 slices per channel

// vert_k geometry
#define VB 10                // LDS bounce batch rows (VCHUNK % VB == 0)
#define VXT 16               // x-tile width
#define VCHUNK 100           // output rows per block (mult of 25 and of VB)
// horiz_nms_k geometry (R13 known-best: 512 threads, 32 vt rows, 30 screened)
#define TH2S 30              // screened rows per block (1080 = 36*30)
#define TW2B 256             // block screen width (pow2)
#define VTC2 282             // vt logical cols (x0-13 .. x0+268)
#define VTS2 283             // vt stride f32 (odd -> bank floor)
#define SMS2 257             // smt stride f32 (odd)
#define CANDC 2048           // LDS candidate cap

// Output layout (floats): px[25*32] py[25*32] score[25*32] mask[25*32] conn[26*32*32]
#define OFF_PY   800
#define OFF_SC   1600
#define OFF_MK   2400
#define OFF_CONN 3200

__device__ __constant__ int LIMBS_d[NLIMB * 2] = {
    1,8, 1,2, 1,5, 2,3, 3,4, 5,6, 6,7, 8,9, 9,10, 10,11, 8,12, 12,13, 13,14,
    1,0, 0,15, 15,16, 0,17, 0,18, 14,19, 19,20, 14,21, 11,22, 22,23, 11,24, 2,17, 5,18
};

__device__ __forceinline__ int symH(int y) {
    if (y < 0) return -1 - y;
    if (y >= H) return 2 * H - 1 - y;
    return y;
}
__device__ __forceinline__ int symW(int x) {
    if (x < 0) return -1 - x;
    if (x >= W) return 2 * W - 1 - x;
    return x;
}

// ---------------------------------------------------------------------------
// Weight init: once per launch. Same FP op order as all prior rounds.
// ---------------------------------------------------------------------------
__global__ void winit_k(double* __restrict__ gw64, float* __restrict__ gw32)
{
    if (threadIdx.x == 0) {
        double wd[25]; double s = 0.0;
        for (int t = 0; t < 25; ++t) {
            double u = (double)(t - 12) / 3.0;
            wd[t] = exp(-0.5 * u * u); s += wd[t];
        }
        for (int t = 0; t < 13; ++t) {
            double w = wd[t] / s;
            gw64[t] = w;
            gw32[t] = (float)w;
        }
    }
}

// ---------------------------------------------------------------------------
// Pass 1: vertical blur, channels-last input read directly (coalesced).
// f64 rolling 25-tap window; stores v32 = fl32(V64) (error <= 3e-8).
// VCHUNK=100: halo 124/100 = 1.24 loads/output.
// ---------------------------------------------------------------------------
__global__ __launch_bounds__(416) void vert_k(
    const float* __restrict__ hm, float* __restrict__ vpl,
    const double* __restrict__ gw64)
{
    __shared__ float ldv[VB][26][17];   // 17.7 KB
    const int tid = threadIdx.x;
    const int x0 = blockIdx.x * VXT;
    const int ys = blockIdx.y * VCHUNK;
    const int c  = tid % 26;
    const int xo = tid / 26;           // 0..15
    const int gx = x0 + xo;

    double ws[13];
    #pragma unroll
    for (int t = 0; t < 13; ++t) ws[t] = gw64[t];   // uniform -> scalar loads

    const size_t cstr = (size_t)W * NCH;
    const size_t base = (size_t)gx * NCH + c;
    const bool yint = (ys >= 12) && (ys + VCHUNK + 11 < H);

    double win[25];
    if (yint) {
        const float* p0 = hm + (size_t)(ys - 12) * cstr + base;
        #pragma unroll
        for (int k = 0; k < 24; ++k) { win[k] = (double)*p0; p0 += cstr; }
    } else {
        #pragma unroll
        for (int k = 0; k < 24; ++k) {
            int ry = symH(ys - 12 + k);
            win[k] = (double)hm[(size_t)ry * cstr + base];
        }
    }
    win[24] = 0.0;

    const float* pn = hm + (size_t)symH(ys + 12) * cstr + base;  // +12 row (fast path)

    #pragma unroll 1
    for (int blk = 0; blk < VCHUNK; blk += 25) {
        #pragma unroll
        for (int p = 0; p < 25; ++p) {
            const int yo = blk + p;
            const int y  = ys + yo;
            double nv;
            if (yint) { nv = (double)*pn; pn += cstr; }
            else      { int ry = symH(y + 12); nv = (double)hm[(size_t)ry * cstr + base]; }
            win[(p + 24) % 25] = nv;
            double acc = 0.0;
            #pragma unroll
            for (int t = 0; t < 25; ++t)
                acc = fma(ws[t < 13 ? t : 24 - t], win[(p + t) % 25], acc);
            if (c < 25) ldv[yo % VB][c][xo] = (float)acc;
            if ((yo % VB) == VB - 1) {
                __syncthreads();
                const int c2 = tid >> 4, x2 = tid & 15;
                if (c2 < 25) {
                    const int yb = ys + yo - (VB - 1);
                    #pragma unroll
                    for (int i = 0; i < VB; ++i) {
                        int yr = yb + i;
                        if (yr < H)
                            vpl[(size_t)c2 * HWSZ + (size_t)yr * W + x0 + x2] = ldv[i][c2][x2];
                    }
                }
                __syncthreads();
            }
        }
    }
}

// ---------------------------------------------------------------------------
// Pass 2 (R13 known-best): f32 horizontal blur + NMS screen. 512 threads =
// 32 vt rows x 16 col-groups; 30 screened rows/block. Direct-LDS FMA reads.
// Per-pixel tap order identical to R9-R13 -> s values bit-identical.
// ---------------------------------------------------------------------------
__global__ __launch_bounds__(512) void horiz_nms_k(
    const float* __restrict__ vpl, const float* __restrict__ hm,
    float* __restrict__ cval, int* __restrict__ cidx,
    int* __restrict__ counters, unsigned int* __restrict__ blg,
    const float* __restrict__ gw32, int cap)
{
    __shared__ __align__(16) float ubuf[32 * VTS2];  // 36.2 KB, vt/smt overlay
    float (*vt)[VTS2]  = reinterpret_cast<float(*)[VTS2]>(ubuf);
    float (*smt)[SMS2] = reinterpret_cast<float(*)[SMS2]>(ubuf);
    __shared__ unsigned short cand[CANDC];           // 4 KB
    __shared__ unsigned int bl[1024];                // 4 KB
    __shared__ int lcount, bcount, gbase, gbase2;

    const int tid = threadIdx.x;
    const int r   = tid & 31;          // compute row 0..31
    const int g   = tid >> 5;          // col group 0..15
    const int ch  = blockIdx.z;
    const int x0  = blockIdx.x * TW2B;
    const int y0  = blockIdx.y * TH2S;
    const float* vp = vpl + (size_t)ch * HWSZ;

    if (tid == 0) { lcount = 0; bcount = 0; }
    float w32[13];
    #pragma unroll
    for (int t = 0; t < 13; ++t) w32[t] = gw32[t];   // uniform -> scalar loads

    // ---- load vt: thread (lr = tid>>4, lc0 = tid&15) loads cols lc0+16j
    {
        const int lr  = tid >> 4;      // 0..31
        const int lc0 = tid & 15;
        int gy = y0 - 1 + lr;
        gy = gy < 0 ? 0 : (gy >= H ? H - 1 : gy);
        const float* rowp = vp + (size_t)gy * W;
        const bool xint = (x0 >= 13) && (x0 + (VTC2 - 13) <= W);
        if (xint) {
            const float* p = rowp + (x0 - 13) + lc0;
            #pragma unroll
            for (int j = 0; j < 18; ++j) {
                int cc = lc0 + 16 * j;
                if (cc < VTC2) vt[lr][cc] = p[16 * j];
            }
        } else {
            #pragma unroll
            for (int j = 0; j < 18; ++j) {
                int cc = lc0 + 16 * j;
                if (cc < VTC2) vt[lr][cc] = rowp[symW(x0 - 13 + cc)];
            }
        }
    }
    __syncthreads();   // also publishes lcount/bcount init

    // ---- horizontal: a[k] = s(y0-1+r, x0 - 1 + g*16 + k), k = 0..17
    float a[18];
    #pragma unroll
    for (int k = 0; k < 18; ++k) a[k] = 0.f;
    {
        const float* vrow = &vt[r][g * 16];
        #pragma unroll
        for (int t = 0; t < 42; ++t) {
            float x = vrow[t];
            #pragma unroll
            for (int k = 0; k < 18; ++k)
                if (t >= k && t < k + 25) {
                    int wi = t - k; wi = wi < 13 ? wi : 24 - wi;
                    a[k] = fmaf(w32[wi], x, a[k]);   // tap-ascending, same as R9-R13
                }
        }
    }
    __syncthreads();   // all vt reads done -> safe to overlay smt

    // ---- smt[r][j] = s(y0-1+r, x0+j), OOB rows/cols zeroed (z_row/z_col)
    const int gy_r = y0 - 1 + r;
    {
        const bool rowok = (gy_r >= 0 && gy_r < H);
        #pragma unroll
        for (int k = 1; k <= 16; ++k) {
            int j = g * 16 + k - 1;
            int gxj = x0 + j;
            smt[r][j] = (rowok && gxj < W) ? a[k] : 0.f;
        }
    }
    __syncthreads();

    // ---- screen: threads r=1..30 screen their own 16 cols
    if (r >= 1 && r <= TH2S && gy_r < H) {
        const float* up = &smt[r - 1][g * 16];
        const float* dn = &smt[r + 1][g * 16];
        const int ly = r - 1;
        #pragma unroll
        for (int k = 0; k < 16; ++k) {
            int gx = x0 + g * 16 + k;
            if (gx >= W) continue;
            float s  = a[k + 1];
            float lv = (gx == 0) ? 0.f : a[k];
            float rv = (gx + 1 >= W) ? 0.f : a[k + 2];
            float dT = s - 0.1f;
            float d0 = s - up[k];
            float d1 = s - dn[k];
            float d2 = s - lv;
            float d3 = s - rv;
            int flags = (fabsf(dT) <= EPS1 ? 1 : 0)
                      | (fabsf(d0) <= EPS1 ? 2 : 0)
                      | (fabsf(d1) <= EPS1 ? 4 : 0)
                      | (fabsf(d2) <= EPS1 ? 8 : 0)
                      | (fabsf(d3) <= EPS1 ? 16 : 0);
            if (!flags) {
                if (dT > 0.f && d0 >= 0.f && d1 >= 0.f && d2 >= 0.f && d3 >= 0.f) {
                    int pos = atomicAdd(&lcount, 1);
                    int gpix = (y0 + ly) * W + gx;
                    if (pos < CANDC) cand[pos] = (unsigned short)((ly << 8) | (g * 16 + k));
                    else {  // overflow (improbable): direct global append
                        int p = atomicAdd(&counters[ch], 1);
                        if (p < cap) {
                            cval[(size_t)ch * cap + p] = hm[(size_t)gpix * NCH + ch];
                            cidx[(size_t)ch * cap + p] = gpix;
                        }
                    }
                }
            } else {
                bool fail = (!(flags & 1)  && dT <= 0.f) ||
                            (!(flags & 2)  && d0 <  0.f) ||
                            (!(flags & 4)  && d1 <  0.f) ||
                            (!(flags & 8)  && d2 <  0.f) ||
                            (!(flags & 16) && d3 <  0.f);
                if (!fail) {
                    unsigned int ent = ((unsigned int)ch << 26) | ((unsigned int)flags << 21)
                                     | (unsigned int)((y0 + ly) * W + gx);
                    int bp = atomicAdd(&bcount, 1);
                    if (bp < 1024) bl[bp] = ent;
                    else {
                        int gp = atomicAdd(&counters[32], 1);
                        if (gp < BLCAP) blg[gp] = ent;
                    }
                }
            }
        }
    }
    __syncthreads();

    if (tid == 0) {
        int nl = lcount < CANDC ? lcount : CANDC;
        gbase  = atomicAdd(&counters[ch], nl);
        int nb = bcount < 1024 ? bcount : 1024;
        gbase2 = atomicAdd(&counters[32], nb);
    }
    __syncthreads();
    int n = lcount < CANDC ? lcount : CANDC;
    int b = gbase;
    for (int i = tid; i < n; i += 512) {
        int p = b + i;
        if (p < cap) {
            int e = cand[i];
            int ly = e >> 8, lx = e & 255;
            int gpix = (y0 + ly) * W + (x0 + lx);
            cval[(size_t)ch * cap + p] = hm[(size_t)gpix * NCH + ch];  // original bits
            cidx[(size_t)ch * cap + p] = gpix;
        }
    }
    int nb = bcount < 1024 ? bcount : 1024;
    for (int i = tid; i < nb; i += 512) {
        int gp = gbase2 + i;
        if (gp < BLCAP) blg[gp] = bl[i];
    }
}

// ---------------------------------------------------------------------------
// Stage-2+3 fused recheck. Stage-2: f64 horizontal over v32 row (error <=
// 3e-8); decisive accept/reject at EPS2. Ambiguous entries re-decided INLINE
// with the fully exact 2D f64 eval (wave-uniform rare path).
// ---------------------------------------------------------------------------
__device__ __forceinline__ double smh2(const float* __restrict__ vp,
                                       const double* w64s, int y, int x)
{
    int lane = threadIdx.x & 63;
    double term = 0.0;
    if (lane < 25) {
        int cx = symW(x - RAD + lane);
        int wi = lane < 13 ? lane : 24 - lane;
        term = w64s[wi] * (double)vp[(size_t)y * W + cx];
    }
    #pragma unroll
    for (int off = 16; off > 0; off >>= 1)
        term += __shfl_xor(term, off, 64);
    return __shfl(term, 0, 64);
}

__device__ double sm64_eval(const float* __restrict__ hm, int ch,
                            const double* w64s, int y, int x)
{
    int lane = threadIdx.x & 63;
    double colsum = 0.0;
    if (lane < 25) {
        int cx = symW(x - RAD + lane);
        float xv[25];
        #pragma unroll
        for (int t = 0; t < 25; t++) {
            int ry = symH(y - RAD + t);
            xv[t] = hm[((size_t)ry * W + cx) * NCH + ch];
        }
        #pragma unroll
        for (int t = 0; t < 25; t++)
            colsum = fma(w64s[t < 13 ? t : 24 - t], (double)xv[t], colsum);
    }
    double acc = 0.0;
    for (int ci = 0; ci < 25; ci++) {
        double cs = __shfl(colsum, ci, 64);
        acc = fma(w64s[ci < 13 ? ci : 24 - ci], cs, acc);
    }
    return acc;
}

__global__ __launch_bounds__(64) void recheck_k(
    const float* __restrict__ vpl, const float* __restrict__ hm,
    float* __restrict__ cval, int* __restrict__ cidx,
    int* __restrict__ counters, const unsigned int* __restrict__ blg,
    const double* __restrict__ gw64, int cap)
{
    __shared__ double w64s[13];
    const int tid = threadIdx.x;
    if (tid < 13) w64s[tid] = gw64[tid];
    __syncthreads();

    int total = counters[32];
    if (total > BLCAP) total = BLCAP;
    for (int e = blockIdx.x; e < total; e += gridDim.x) {
        unsigned int ent = blg[e];
        int ch    = (int)(ent >> 26);
        int flags = (int)((ent >> 21) & 31);
        int gpix  = (int)(ent & 0x1FFFFFu);
        int gy = gpix / W, gx = gpix - gy * W;
        const float* vp = vpl + (size_t)ch * HWSZ;

        double sc = smh2(vp, w64s, gy, gx);
        bool dead = false; bool esc = false;
        if (flags & 1) {
            double d = sc - 0.1;
            if (d <= -EPS2) dead = true; else if (d < EPS2) esc = true;
        }
        if (!dead && (flags & 2)) {
            double nv = (gy - 1 >= 0) ? smh2(vp, w64s, gy - 1, gx) : 0.0;
            double d = sc - nv;
            if (d <= -EPS2) dead = true; else if (d < EPS2) esc = true;
        }
        if (!dead && (flags & 4)) {
            double nv = (gy + 1 < H) ? smh2(vp, w64s, gy + 1, gx) : 0.0;
            double d = sc - nv;
            if (d <= -EPS2) dead = true; else if (d < EPS2) esc = true;
        }
        if (!dead && (flags & 8)) {
            double nv = (gx - 1 >= 0) ? smh2(vp, w64s, gy, gx - 1) : 0.0;
            double d = sc - nv;
            if (d <= -EPS2) dead = true; else if (d < EPS2) esc = true;
        }
        if (!dead && (flags & 16)) {
            double nv = (gx + 1 < W) ? smh2(vp, w64s, gy, gx + 1) : 0.0;
            double d = sc - nv;
            if (d <= -EPS2) dead = true; else if (d < EPS2) esc = true;
        }
        bool accept = false;
        if (!dead && !esc) accept = true;
        else if (!dead && esc) {
            // exact 2D re-decision (rare; wave-uniform branch)
            double sE = sm64_eval(hm, ch, w64s, gy, gx);
            bool ok = (flags & 1) ? (sE > 0.1) : true;
            if (ok && (flags & 2))  { double nv = (gy - 1 >= 0) ? sm64_eval(hm, ch, w64s, gy - 1, gx) : 0.0; ok = (sE >= nv); }
            if (ok && (flags & 4))  { double nv = (gy + 1 <  H) ? sm64_eval(hm, ch, w64s, gy + 1, gx) : 0.0; ok = (sE >= nv); }
            if (ok && (flags & 8))  { double nv = (gx - 1 >= 0) ? sm64_eval(hm, ch, w64s, gy, gx - 1) : 0.0; ok = (sE >= nv); }
            if (ok && (flags & 16)) { double nv = (gx + 1 <  W) ? sm64_eval(hm, ch, w64s, gy, gx + 1) : 0.0; ok = (sE >= nv); }
            accept = ok;
        }
        if (accept && tid == 0) {
            int p = atomicAdd(&counters[ch], 1);
            if (p < cap) {
                cval[(size_t)ch * cap + p] = hm[(size_t)gpix * NCH + ch];
                cidx[(size_t)ch * cap + p] = gpix;
            }
        }
    }
}

// ---------------------------------------------------------------------------
// Fallback: exact-f64 gather version (used only if ws too small)
// ---------------------------------------------------------------------------
#define TH 32
#define TW 64
#define LR (TH + 2*RAD + 2)
#define LC 90
#define VRR 34
#define VC (TW + 2*RAD + 2)
#define SR 34
#define SC 66
__global__ __launch_bounds__(256) void blur_peaks_gather(
    const float* __restrict__ hm,
    float* __restrict__ cval, int* __restrict__ cidx,
    int* __restrict__ counters, int cap)
{
    __shared__ float  in_t[LR][LC];
    __shared__ double v[VRR][VC];
    __shared__ double smv[SR][SC];
    __shared__ double wgt[2 * RAD + 1];
    __shared__ double wsum;

    const int tid = threadIdx.x;
    const int ch  = blockIdx.x;
    const int x0  = blockIdx.y * TW;
    const int y0  = blockIdx.z * TH;

    if (tid < 2 * RAD + 1) {
        double t = (double)(tid - RAD) / 3.0;
        wgt[tid] = exp(-0.5 * t * t);
    }
    __syncthreads();
    if (tid == 0) {
        double s = 0.0;
        for (int i = 0; i < 2 * RAD + 1; i++) s += wgt[i];
        wsum = s;
    }
    __syncthreads();
    if (tid < 2 * RAD + 1) wgt[tid] /= wsum;

    for (int i = tid; i < LR * LC; i += 256) {
        int r = i / LC, c = i % LC;
        int gy = symH(y0 - RAD - 1 + r);
        int gx = symW(x0 - RAD - 1 + c);
        in_t[r][c] = hm[((size_t)gy * W + gx) * NCH + ch];
    }
    __syncthreads();

    for (int i = tid; i < VRR * VC; i += 256) {
        int r = i / VC, c = i % VC;
        double acc = 0.0;
        #pragma unroll
        for (int t = 0; t < 2 * RAD + 1; t++)
            acc = fma(wgt[t], (double)in_t[r + t][c], acc);
        v[r][c] = acc;
    }
    __syncthreads();

    for (int i = tid; i < SR * SC; i += 256) {
        int r = i / SC, cc = i % SC;
        int gy = y0 - 1 + r;
        int gx = x0 - 1 + cc;
        double acc = 0.0;
        if (gy >= 0 && gy < H && gx >= 0 && gx < W) {
            #pragma unroll
            for (int t = 0; t < 2 * RAD + 1; t++)
                acc = fma(wgt[t], v[r][cc + t], acc);
        }
        smv[r][cc] = acc;
    }
    __syncthreads();

    for (int i = tid; i < TH * TW; i += 256) {
        int ly = i / TW, lx = i % TW;
        int gy = y0 + ly, gx = x0 + lx;
        if (gy >= H || gx >= W) continue;
        double s = smv[ly + 1][lx + 1];
        if (s > 0.1 &&
            s >= smv[ly][lx + 1] && s >= smv[ly + 2][lx + 1] &&
            s >= smv[ly + 1][lx] && s >= smv[ly + 1][lx + 2]) {
            float val = in_t[ly + RAD + 1][lx + RAD + 1];
            int pos = atomicAdd(&counters[ch], 1);
            if (pos < cap) {
                cval[(size_t)ch * cap + pos] = val;
                cidx[(size_t)ch * cap + pos] = gy * W + gx;
            }
        }
    }
}

// ---------------------------------------------------------------------------
// Kernel B1: per-(channel, slice) exact top-32 -> packed keys to s1.
// ---------------------------------------------------------------------------
#define BT 128
__global__ __launch_bounds__(BT) void topk1_kernel(
    const float* __restrict__ cval, const int* __restrict__ cidx,
    const int* __restrict__ counters, int cap,
    unsigned long long* __restrict__ s1)
{
    __shared__ unsigned long long lk[KTOP * BT];
    __shared__ unsigned long long rk[BT];
    __shared__ int rw[BT];
    __shared__ int winner;

    const int tid = threadIdx.x;
    const int sl  = blockIdx.x;   // slice
    const int ch  = blockIdx.y;
    int n = counters[ch];
    if (n > cap) n = cap;

    int cnt = 0;
    for (int j = sl * BT + tid; j < n; j += NS * BT) {
        float v = cval[(size_t)ch * cap + j];
        unsigned int u = __float_as_uint(v);
        u = (u & 0x80000000u) ? ~u : (u | 0x80000000u);   // monotonic key
        unsigned long long key =
            ((unsigned long long)u << 32) |
            (unsigned int)(0xFFFFFFFFu - (unsigned int)cidx[(size_t)ch * cap + j]);
        if (cnt == KTOP) {
            if (key <= lk[(KTOP - 1) * BT + tid]) continue;
            cnt = KTOP - 1;
        }
        int i = cnt;
        while (i > 0 && key > lk[(i - 1) * BT + tid]) {
            lk[i * BT + tid] = lk[(i - 1) * BT + tid];
            i--;
        }
        lk[i * BT + tid] = key;
        cnt++;
    }
    int cur = 0;
    __syncthreads();

    for (int k = 0; k < KTOP; k++) {
        rk[tid] = (cur < cnt) ? lk[cur * BT + tid] : 0ULL;
        rw[tid] = tid;
        __syncthreads();
        for (int s = BT / 2; s > 0; s >>= 1) {
            if (tid < s) {
                if (rk[tid + s] > rk[tid]) { rk[tid] = rk[tid + s]; rw[tid] = rw[tid + s]; }
            }
            __syncthreads();
        }
        if (tid == 0) {
            winner = rw[0];
            s1[((size_t)ch * NS + sl) * KTOP + k] = rk[0];   // 0 = empty pad
        }
        __syncthreads();
        if (tid == winner && cur < cnt) cur++;
        __syncthreads();
    }
}

// ---------------------------------------------------------------------------
// Kernel B2: per-channel merge of NS*32=512 keys via LDS bitonic sort (desc).
// ---------------------------------------------------------------------------
__global__ __launch_bounds__(BT) void topk2_kernel(
    const unsigned long long* __restrict__ s1,
    const int* __restrict__ counters, int cap, float* __restrict__ out)
{
    __shared__ unsigned long long sk[NS * KTOP];   // 512 keys, 4 KB
    const int tid = threadIdx.x;
    const int ch  = blockIdx.x;

    for (int i = tid; i < NS * KTOP; i += BT)
        sk[i] = s1[(size_t)ch * NS * KTOP + i];
    __syncthreads();

    for (int k = 2; k <= NS * KTOP; k <<= 1) {
        for (int j = k >> 1; j > 0; j >>= 1) {
            for (int t = tid; t < NS * KTOP; t += BT) {
                int ixj = t ^ j;
                if (ixj > t) {
                    unsigned long long a = sk[t], b = sk[ixj];
                    bool sw = ((t & k) == 0) ? (a < b) : (a > b);
                    if (sw) { sk[t] = b; sk[ixj] = a; }
                }
            }
            __syncthreads();
        }
    }

    int n = counters[ch];
    if (n > cap) n = cap;
    if (tid < KTOP) {
        unsigned long long bk = sk[tid];
        float px, py, sc, mk;
        if (bk == 0ULL) {
            int fake = tid - n; if (fake < 0) fake = 0;
            px = (float)(fake % W); py = (float)(fake / W); sc = 0.f; mk = 0.f;
        } else {
            unsigned int u = (unsigned int)(bk >> 32);
            unsigned int fb = (u & 0x80000000u) ? (u ^ 0x80000000u) : ~u;
            float v = __uint_as_float(fb);
            int idx = (int)(0xFFFFFFFFu - (unsigned int)(bk & 0xFFFFFFFFu));
            px = (float)(idx % W); py = (float)(idx / W); sc = v; mk = 1.f;
        }
        out[ch * KTOP + tid]          = px;
        out[OFF_PY + ch * KTOP + tid] = py;
        out[OFF_SC + ch * KTOP + tid] = sc;
        out[OFF_MK + ch * KTOP + tid] = mk;
    }
}

// ---------------------------------------------------------------------------
// Fallback single-stage top-k (ws-too-small path only)
// ---------------------------------------------------------------------------
__global__ __launch_bounds__(BT) void topk_kernel(
    const float* __restrict__ cval, const int* __restrict__ cidx,
    const int* __restrict__ counters, int cap, float* __restrict__ out)
{
    __shared__ unsigned long long lk[KTOP * BT];
    __shared__ unsigned long long rk[BT];
    __shared__ int rw[BT];
    __shared__ int winner;

    const int tid = threadIdx.x;
    const int ch  = blockIdx.x;
    int n = counters[ch];
    if (n > cap) n = cap;

    int cnt = 0;
    for (int j = tid; j < n; j += BT) {
        float v = cval[(size_t)ch * cap + j];
        unsigned int u = __float_as_uint(v);
        u = (u & 0x80000000u) ? ~u : (u | 0x80000000u);
        unsigned long long key =
            ((unsigned long long)u << 32) |
            (unsigned int)(0xFFFFFFFFu - (unsigned int)cidx[(size_t)ch * cap + j]);
        if (cnt == KTOP) {
            if (key <= lk[(KTOP - 1) * BT + tid]) continue;
            cnt = KTOP - 1;
        }
        int i = cnt;
        while (i > 0 && key > lk[(i - 1) * BT + tid]) {
            lk[i * BT + tid] = lk[(i - 1) * BT + tid];
            i--;
        }
        lk[i * BT + tid] = key;
        cnt++;
    }
    int cur = 0;
    __syncthreads();

    for (int k = 0; k < KTOP; k++) {
        rk[tid] = (cur < cnt) ? lk[cur * BT + tid] : 0ULL;
        rw[tid] = tid;
        __syncthreads();
        for (int s = BT / 2; s > 0; s >>= 1) {
            if (tid < s) {
                if (rk[tid + s] > rk[tid]) { rk[tid] = rk[tid + s]; rw[tid] = rw[tid + s]; }
            }
            __syncthreads();
        }
        if (tid == 0) {
            winner = rw[0];
            unsigned long long bk = rk[0];
            float px, py, sc, mk;
            if (bk == 0ULL) {
                int fake = k - n; if (fake < 0) fake = 0;
                px = (float)(fake % W); py = (float)(fake / W); sc = 0.f; mk = 0.f;
            } else {
                unsigned int u = (unsigned int)(bk >> 32);
                unsigned int fb = (u & 0x80000000u) ? (u ^ 0x80000000u) : ~u;
                float v = __uint_as_float(fb);
                int idx = (int)(0xFFFFFFFFu - (unsigned int)(bk & 0xFFFFFFFFu));
                px = (float)(idx % W); py = (float)(idx / W); sc = v; mk = 1.f;
            }
            out[ch * KTOP + k]          = px;
            out[OFF_PY + ch * KTOP + k] = py;
            out[OFF_SC + ch * KTOP + k] = sc;
            out[OFF_MK + ch * KTOP + k] = mk;
        }
        __syncthreads();
        if (tid == winner && cur < cnt) cur++;
        __syncthreads();
    }
}

// ---------------------------------------------------------------------------
// Kernel C: limb connection scores (26 x 32 x 32)
// ---------------------------------------------------------------------------
__global__ __launch_bounds__(1024) void limbs_kernel(
    const float* __restrict__ pk, const float* __restrict__ paf,
    float* __restrict__ out)
{
    const int l = blockIdx.x;
    const int tid = threadIdx.x;
    const int i = tid >> 5;
    const int j = tid & 31;
    const int A = LIMBS_d[2 * l], B = LIMBS_d[2 * l + 1];

    float ax = pk[A * KTOP + i],          ay = pk[OFF_PY + A * KTOP + i];
    float ma = pk[OFF_MK + A * KTOP + i];
    float bx = pk[B * KTOP + j],          by = pk[OFF_PY + B * KTOP + j];
    float mb = pk[OFF_MK + B * KTOP + j];

    float vx = bx - ax, vy = by - ay;
    float norm = sqrtf(vx * vx + vy * vy) + 1e-10f;
    float ux = vx / norm, uy = vy / norm;

    const float step = 1.0f / 9.0f;
    float sum = 0.f;
    #pragma unroll
    for (int m = 0; m < MID; m++) {
        float t = (float)m * step;
        int sx = (int)rintf(ax + vx * t);
        int sy = (int)rintf(ay + vy * t);
        const float* p = paf + ((size_t)sy * W + sx) * (2 * NLIMB) + 2 * l;
        sum += p[0] * ux + p[1] * uy;
    }
    float score = sum / (float)MID;
    score = score < 0.f ? 0.f : (score > 1.f ? 1.f : score);
    float res = (ma != 0.f && mb != 0.f) ? score : 0.f;
    out[OFF_CONN + l * (KTOP * KTOP) + i * KTOP + j] = res;
}

// ---------------------------------------------------------------------------
extern "C" void kernel_launch(void* const* d_in, const int* in_sizes, int n_in,
                              void* d_out, int out_size, void* d_ws, size_t ws_size,
                              hipStream_t stream)
{
    const float* hm  = (const float*)d_in[0];
    const float* paf = (const float*)d_in[1];
    float* out = (float*)d_out;

    const size_t vpl_bytes = (size_t)NPART * HWSZ * sizeof(float);  // ~207.4 MB
    const size_t bl_bytes  = (size_t)BLCAP * 4;                     // 4 MB
    const size_t s1_bytes  = (size_t)NPART * NS * KTOP * 8;         // 100 KB
    const size_t head = 512;   // counters [0,256) + weights [256,512)

    bool pathA = false;
    int cap = 1;
    if (ws_size > head + vpl_bytes + bl_bytes + s1_bytes
                 + (size_t)NPART * 8 * 4096 + 1024) {
        size_t avail = ws_size - head - vpl_bytes - bl_bytes - s1_bytes - 1024;
        long long c = (long long)(avail / ((size_t)NPART * 8));
        cap = c > 65536 ? 65536 : (int)c;
        pathA = true;
    } else {
        size_t avail = ws_size > head ? ws_size - head : 0;
        long long c = (long long)(avail / ((size_t)NPART * 8));
        cap = c > 65536 ? 65536 : (int)c;
        if (cap < 1) cap = 1;
    }

    int*    counters = (int*)d_ws;
    double* gw64 = (double*)((char*)d_ws + 256);    // 13 doubles
    float*  gw32 = (float*)((char*)d_ws + 384);     // 13 floats
    float* cval = (float*)((char*)d_ws + head);
    int*   cidx = (int*)(cval + (size_t)NPART * cap);
    unsigned long long* s1 = (unsigned long long*)(cidx + (size_t)NPART * cap);
    unsigned int* blg = (unsigned int*)(s1 + (pathA ? (size_t)NPART * NS * KTOP : 0));
    float* vpl = (float*)(blg + (pathA ? (size_t)BLCAP : 0));
    vpl = (float*)(((uintptr_t)vpl + 255) & ~(uintptr_t)255);

    hipMemsetAsync(d_ws, 0, 256, stream);

    if (pathA) {
        winit_k<<<1, 64, 0, stream>>>(gw64, gw32);
        dim3 g1(W / VXT, (H + VCHUNK - 1) / VCHUNK);                // 120 x 11
        vert_k<<<g1, 416, 0, stream>>>(hm, vpl, gw64);
        dim3 g2((W + TW2B - 1) / TW2B, H / TH2S, NPART);            // 8 x 36 x 25
        horiz_nms_k<<<g2, 512, 0, stream>>>(vpl, hm, cval, cidx, counters, blg, gw32, cap);
        recheck_k<<<2048, 64, 0, stream>>>(vpl, hm, cval, cidx, counters, blg, gw64, cap);
        dim3 gt(NS, NPART);
        topk1_kernel<<<gt, BT, 0, stream>>>(cval, cidx, counters, cap, s1);
        topk2_kernel<<<NPART, BT, 0, stream>>>(s1, counters, cap, out);
    } else {
        dim3 gA(NPART, (W + TW - 1) / TW, (H + TH - 1) / TH);
        blur_peaks_gather<<<gA, 256, 0, stream>>>(hm, cval, cidx, counters, cap);
        topk_kernel<<<NPART, BT, 0, stream>>>(cval, cidx, counters, cap, out);
    }
    limbs_kernel<<<NLIMB, 1024, 0, stream>>>(out, paf, out);
}